// Round 10
// baseline (142.175 us; speedup 1.0000x reference)
//
#include <hip/hip_runtime.h>
#include <hip/hip_bf16.h>
#include <math.h>

#define NA 2048   // agents (2^11)
#define TT 20     // timesteps
#define KK 32     // neighbors
#define CC 32     // in channels
#define OO 64     // out channels / hidden
#define GG 256    // 4*OO gates
#define SW 72     // feat_sh row stride in shorts

typedef __attribute__((ext_vector_type(8))) short short8;
typedef __attribute__((ext_vector_type(4))) float float4v;
typedef __attribute__((ext_vector_type(4))) unsigned uint4v;

// s_waitcnt with vmcnt(n), lgkm/exp unconstrained (gfx9 encoding).
#define WAITVM(n) __builtin_amdgcn_s_waitcnt(0x0F70 | (n))

__device__ __forceinline__ float fast_rcp(float x) {
    return __builtin_amdgcn_rcpf(x);
}
__device__ __forceinline__ float sigm(float x) {
    return fast_rcp(1.f + __expf(-x));
}
__device__ __forceinline__ float tanh_fast(float x) {
    return 1.f - 2.f * fast_rcp(1.f + __expf(2.f * x));
}
// bf16 RNE on raw bits (ties-to-even; NaN not expected here).
__device__ __forceinline__ unsigned cvt_rne(float f) {
    unsigned u = __float_as_uint(f);
    return (u + 0x7FFFu + ((u >> 16) & 1u)) >> 16;
}
__device__ __forceinline__ unsigned pack2(float a, float b) {
    return cvt_rne(a) | (cvt_rne(b) << 16);
}
__device__ __forceinline__ float bf_lo(unsigned u) {
    return __uint_as_float(u << 16);
}
__device__ __forceinline__ float bf_hi(unsigned u) {
    return __uint_as_float(u & 0xffff0000u);
}
// Async global->LDS, 16B per lane. Dest = wave-uniform base + lane*16.
__device__ __forceinline__ void async16(const void* g, void* l) {
    __builtin_amdgcn_global_load_lds(
        (const __attribute__((address_space(1))) unsigned*)g,
        (__attribute__((address_space(3))) unsigned*)l, 16, 0, 0);
}

// P[t][n][o] = sum_c x[n][t][c] * conv_w[o][c], stored bf16 (128B rows).
// Block 0 pre-converts w_ih/w_hh to bf16 and precomputes the folded gate
// bias (b_ih + b_hh + conv_b @ w_ih^T).
__global__ __launch_bounds__(256) void proj_kernel(
    const float* __restrict__ x, const float* __restrict__ conv_w,
    const float* __restrict__ conv_b, const float* __restrict__ w_ih,
    const float* __restrict__ w_hh, const float* __restrict__ b_ih,
    const float* __restrict__ b_hh,
    __hip_bfloat16* __restrict__ P, unsigned short* __restrict__ wihb,
    unsigned short* __restrict__ whhb, float* __restrict__ biasT)
{
    const int tid = threadIdx.x;
    if (blockIdx.x == 0) {   // prep block
        for (int e = tid; e < 4 * OO * OO; e += 256) {
            wihb[e] = (unsigned short)cvt_rne(w_ih[e]);
            whhb[e] = (unsigned short)cvt_rne(w_hh[e]);
        }
        float bj = b_ih[tid] + b_hh[tid];
        #pragma unroll
        for (int o = 0; o < OO; o += 4) {
            float4 cb = *(const float4*)(conv_b + o);
            float4 wr = *(const float4*)(w_ih + (size_t)tid * OO + o);
            bj = fmaf(cb.x, wr.x, bj); bj = fmaf(cb.y, wr.y, bj);
            bj = fmaf(cb.z, wr.z, bj); bj = fmaf(cb.w, wr.w, bj);
        }
        biasT[tid] = bj;
        return;
    }
    const int lane = tid & 63;
    const int wv = tid >> 6;
    float w[CC];
    #pragma unroll
    for (int c = 0; c < CC; c += 4) {
        float4 v = *(const float4*)(conv_w + lane * CC + c);
        w[c] = v.x; w[c + 1] = v.y; w[c + 2] = v.z; w[c + 3] = v.w;
    }
    const int rbase = (blockIdx.x - 1) * 16 + wv * 4;
    #pragma unroll
    for (int i = 0; i < 4; ++i) {
        int r = rbase + i;                    // r = n*TT + t (x row order)
        const float* xr = x + (size_t)r * CC;
        float a0 = 0.f, a1 = 0.f;
        #pragma unroll
        for (int c = 0; c < CC; c += 8) {
            float4 v = *(const float4*)(xr + c);
            float4 u = *(const float4*)(xr + c + 4);
            a0 = fmaf(v.x, w[c], a0);     a0 = fmaf(v.y, w[c + 1], a0);
            a0 = fmaf(v.z, w[c + 2], a0); a0 = fmaf(v.w, w[c + 3], a0);
            a1 = fmaf(u.x, w[c + 4], a1); a1 = fmaf(u.y, w[c + 5], a1);
            a1 = fmaf(u.z, w[c + 6], a1); a1 = fmaf(u.w, w[c + 7], a1);
        }
        int n = r / TT;
        int t = r - n * TT;
        ((unsigned short*)P)[(((size_t)t << 11) + n) * OO + lane] =
            (unsigned short)cvt_rne(a0 + a1);
    }
}

// Gather-max + gate MFMA, pipelined async-gather edition.
// R9 was 36us: per-block vmcnt(0) full-drain exposed L2 latency 10x per CU
// with only 2 blocks/CU overlap. Here: 128-thread blocks (4/CU), each wave
// owns 8 rows = 4 sub-tiles of 2 rows, double-buffered private slab,
// fine-grained vmcnt(9) pipeline (issue s+1, wait 9, reduce s — never a
// mid-stream drain). A-indices staged per-wave in LDS (lgkm counter, off
// the vmcnt pipeline). One __syncthreads, placed where vmcnt ~ 0.
__global__ __launch_bounds__(128, 2) void gatemm_kernel(
    const __hip_bfloat16* __restrict__ P, const int* __restrict__ A,
    const unsigned short* __restrict__ wihb, const float* __restrict__ biasT,
    __hip_bfloat16* __restrict__ gx)
{
    extern __shared__ __align__(16) char slab_raw[];   // 2 waves x 16KB
    __shared__ int A_buf[2][256];                       // 8 rows x 32 idx/wave
    __shared__ __align__(16) unsigned short feat_sh[16 * SW];

    const int tid = threadIdx.x;
    const int lane = tid & 63;
    const int wv = tid >> 6;            // 0..1
    const int l15 = lane & 15;
    const int q = lane >> 4;

    const int bs = (blockIdx.x & 7) * 320 + (blockIdx.x >> 3);  // XCD swizzle
    const int r0 = bs << 4;                  // first row, r = t*NA + n
    const int t = r0 >> 11;
    const int n0 = r0 & (NA - 1);
    const unsigned short* Pb = (const unsigned short*)P + ((size_t)t << 17);

    // --- pre-issue batch (25 vmcnt entries, all before the gather stream;
    // in-order retire keeps downstream counts exact) ---
    int4 av = ((const int4*)(A + ((size_t)(r0 + wv * 8) << 5)))[lane];
    float bv[8];
    short8 bfrag[8][2];
    #pragma unroll
    for (int cg = 0; cg < 8; ++cg) {
        int j = wv * 128 + cg * 16 + l15;
        bv[cg] = biasT[j];
        #pragma unroll
        for (int ks = 0; ks < 2; ++ks)
            bfrag[cg][ks] =
                *(const short8*)(wihb + ((size_t)j << 6) + ks * 32 + q * 8);
    }
    ((int4*)A_buf[wv])[lane] = av;      // compiler waits on av only

    const int r1 = lane >> 5;           // 0..1: row within sub-tile
    const int kp = (lane >> 3) & 3;     // neighbor phase (k mod 4)
    const int oc = lane & 7;            // channel oct (8 bf16 = 16B)
    char* myslab = slab_raw + wv * 16384;

    uint4v sv[4];
    // issue sub-tile s into buffer b: 8 lds-gathers + 1 self vgpr load
    #define ISSUE(s, b)                                                      \
        {                                                                    \
            const int rr = (s) * 2 + r1;                                     \
            int idx[8];                                                      \
            _Pragma("unroll")                                                \
            for (int g = 0; g < 8; ++g)                                      \
                idx[g] = A_buf[wv][rr * KK + g * 4 + kp];                    \
            char* dst = myslab + (b) * 8192;                                 \
            _Pragma("unroll")                                                \
            for (int g = 0; g < 8; ++g)                                      \
                async16(Pb + ((size_t)idx[g] << 6) + oc * 8, dst + g * 1024);\
            sv[s] = *(const uint4v*)(                                        \
                Pb + ((size_t)(n0 + wv * 8 + rr) << 6) + oc * 8);            \
        }

    ISSUE(0, 0)
    #pragma unroll
    for (int s = 0; s < 4; ++s) {
        if (s == 0) ISSUE(1, 1)
        if (s == 1) ISSUE(2, 0)
        if (s == 2) ISSUE(3, 1)
        if (s < 3) { WAITVM(9); } else { WAITVM(0); }

        // reduce sub-tile s from buffer s&1 (lane-linear, conflict-free)
        const unsigned short* ms =
            (const unsigned short*)(myslab + (s & 1) * 8192);
        float mx[8];
        #pragma unroll
        for (int e = 0; e < 8; ++e) mx[e] = -INFINITY;
        #pragma unroll
        for (int g = 0; g < 8; ++g) {
            uint4v v = *(const uint4v*)(ms + g * 512 + lane * 8);
            mx[0] = fmaxf(mx[0], bf_lo(v[0])); mx[1] = fmaxf(mx[1], bf_hi(v[0]));
            mx[2] = fmaxf(mx[2], bf_lo(v[1])); mx[3] = fmaxf(mx[3], bf_hi(v[1]));
            mx[4] = fmaxf(mx[4], bf_lo(v[2])); mx[5] = fmaxf(mx[5], bf_hi(v[2]));
            mx[6] = fmaxf(mx[6], bf_lo(v[3])); mx[7] = fmaxf(mx[7], bf_hi(v[3]));
        }
        #pragma unroll
        for (int e = 0; e < 8; ++e) {
            mx[e] = fmaxf(mx[e], __shfl_xor(mx[e], 8, 64));
            mx[e] = fmaxf(mx[e], __shfl_xor(mx[e], 16, 64));
        }
        if (kp == 0) {
            uint4v s4 = sv[s];
            uint4v pk;
            pk[0] = pack2(mx[0] - bf_lo(s4[0]), mx[1] - bf_hi(s4[0]));
            pk[1] = pack2(mx[2] - bf_lo(s4[1]), mx[3] - bf_hi(s4[1]));
            pk[2] = pack2(mx[4] - bf_lo(s4[2]), mx[5] - bf_hi(s4[2]));
            pk[3] = pack2(mx[6] - bf_lo(s4[3]), mx[7] - bf_hi(s4[3]));
            const int frow = wv * 8 + s * 2 + r1;
            *(uint4v*)&feat_sh[frow * SW + oc * 8] = pk;
        }
    }
    #undef ISSUE

    __syncthreads();   // feat complete; vmcnt naturally ~0 here

    // Gate MFMA: 16 rows x this wave's 128 cols, K=64 in 2 steps.
    float4v acc[8];
    #pragma unroll
    for (int cg = 0; cg < 8; ++cg) acc[cg] = (float4v){0.f, 0.f, 0.f, 0.f};
    #pragma unroll
    for (int ks = 0; ks < 2; ++ks) {
        short8 af = *(const short8*)(&feat_sh[l15 * SW + ks * 32 + q * 8]);
        #pragma unroll
        for (int cg = 0; cg < 8; ++cg)
            acc[cg] = __builtin_amdgcn_mfma_f32_16x16x32_bf16(
                af, bfrag[cg][ks], acc[cg], 0, 0, 0);
    }
    unsigned short* gxp = (unsigned short*)gx;
    #pragma unroll
    for (int cg = 0; cg < 8; ++cg) {
        int j = wv * 128 + cg * 16 + l15;
        #pragma unroll
        for (int rg = 0; rg < 4; ++rg)
            gxp[((size_t)(r0 + q * 4 + rg) << 8) + j] =
                (unsigned short)cvt_rne(acc[cg][rg] + bv[cg]);
    }
}

// Serial recurrence via MFMA: 16 agents/block (128 blocks), R9 structure.
__global__ __launch_bounds__(256, 4) void lstm_kernel(
    const __hip_bfloat16* __restrict__ gx, const unsigned short* __restrict__ whhb,
    float* __restrict__ out)
{
    const int tid = threadIdx.x;
    const int lane = tid & 63;
    const int wv = tid >> 6;          // gate plane
    const int l15 = lane & 15;
    const int q = lane >> 4;
    const int a0 = blockIdx.x * 16;
    const int a = tid >> 4;           // pointwise: agent 0..15
    const int c0 = (tid & 15) * 4;    // pointwise: first channel

    // B-frags from preconverted bf16: B[k][ch] = w_hh[wv*64 + ch][k]
    short8 bfrag[4][2];
    #pragma unroll
    for (int tt2 = 0; tt2 < 4; ++tt2) {
        int row = wv * 64 + tt2 * 16 + l15;
        #pragma unroll
        for (int ks = 0; ks < 2; ++ks)
            bfrag[tt2][ks] =
                *(const short8*)(whhb + ((size_t)row << 6) + ks * 32 + q * 8);
    }

    __shared__ __align__(16) unsigned short h_sh[16 * 72];  // bf16, pad 72
    __shared__ float gp[4][16][68];                         // gate planes

    {   // h = 0
        uint2 z; z.x = 0u; z.y = 0u;
        *(uint2*)&h_sh[a * 72 + c0] = z;
    }
    float cst[4] = {0.f, 0.f, 0.f, 0.f};

    const unsigned short* gxp = (const unsigned short*)gx;
    uint2 gxv[4];
    #pragma unroll
    for (int g = 0; g < 4; ++g)
        gxv[g] = *(const uint2*)(gxp + ((size_t)(a0 + a) << 8) + g * 64 + c0);

    for (int t = 0; t < TT; ++t) {
        __syncthreads();  // h_sh ready (init or previous pointwise)

        float4v acc[4] = {{0.f, 0.f, 0.f, 0.f}, {0.f, 0.f, 0.f, 0.f},
                          {0.f, 0.f, 0.f, 0.f}, {0.f, 0.f, 0.f, 0.f}};
        #pragma unroll
        for (int ks = 0; ks < 2; ++ks) {
            short8 af = *(const short8*)(&h_sh[l15 * 72 + ks * 32 + q * 8]);
            #pragma unroll
            for (int tt2 = 0; tt2 < 4; ++tt2)
                acc[tt2] = __builtin_amdgcn_mfma_f32_16x16x32_bf16(
                    af, bfrag[tt2][ks], acc[tt2], 0, 0, 0);
        }
        #pragma unroll
        for (int tt2 = 0; tt2 < 4; ++tt2)
            #pragma unroll
            for (int rg = 0; rg < 4; ++rg)
                gp[wv][q * 4 + rg][tt2 * 16 + l15] = acc[tt2][rg];

        // prefetch next step's gx while gp settles
        uint2 gxn[4];
        int tn = (t + 1 < TT) ? t + 1 : t;
        #pragma unroll
        for (int g = 0; g < 4; ++g)
            gxn[g] = *(const uint2*)(gxp + (((size_t)tn << 11) + a0 + a) * GG
                                     + g * 64 + c0);
        __syncthreads();  // gp ready

        float4 gv0 = *(const float4*)&gp[0][a][c0];
        float4 gv1 = *(const float4*)&gp[1][a][c0];
        float4 gv2 = *(const float4*)&gp[2][a][c0];
        float4 gv3 = *(const float4*)&gp[3][a][c0];
        float hv[4];
        {
            float gi[4] = {gv0.x + bf_lo(gxv[0].x), gv0.y + bf_hi(gxv[0].x),
                           gv0.z + bf_lo(gxv[0].y), gv0.w + bf_hi(gxv[0].y)};
            float gf[4] = {gv1.x + bf_lo(gxv[1].x), gv1.y + bf_hi(gxv[1].x),
                           gv1.z + bf_lo(gxv[1].y), gv1.w + bf_hi(gxv[1].y)};
            float gz[4] = {gv2.x + bf_lo(gxv[2].x), gv2.y + bf_hi(gxv[2].x),
                           gv2.z + bf_lo(gxv[2].y), gv2.w + bf_hi(gxv[2].y)};
            float go[4] = {gv3.x + bf_lo(gxv[3].x), gv3.y + bf_hi(gxv[3].x),
                           gv3.z + bf_lo(gxv[3].y), gv3.w + bf_hi(gxv[3].y)};
            #pragma unroll
            for (int e = 0; e < 4; ++e) {
                float ig = sigm(gi[e]);
                float fg = sigm(gf[e]);
                float zg = tanh_fast(gz[e]);
                float og = sigm(go[e]);
                cst[e] = fmaf(fg, cst[e], ig * zg);
                hv[e] = og * tanh_fast(cst[e]);
            }
        }
        {
            uint2 pk;
            pk.x = pack2(hv[0], hv[1]);
            pk.y = pack2(hv[2], hv[3]);
            *(uint2*)&h_sh[a * 72 + c0] = pk;
        }
        float4 ho; ho.x = hv[0]; ho.y = hv[1]; ho.z = hv[2]; ho.w = hv[3];
        *(float4*)(out + (((size_t)(a0 + a) * TT + t) << 6) + c0) = ho;
        if (t == TT - 1) {
            size_t hb = (size_t)NA * TT * OO;
            *(float4*)(out + hb + ((size_t)(a0 + a) << 6) + c0) = ho;
            float4 co; co.x = cst[0]; co.y = cst[1]; co.z = cst[2]; co.w = cst[3];
            *(float4*)(out + hb + ((size_t)NA << 6) + ((size_t)(a0 + a) << 6) + c0) = co;
        }
        gxv[0] = gxn[0]; gxv[1] = gxn[1]; gxv[2] = gxn[2]; gxv[3] = gxn[3];
    }
}

extern "C" void kernel_launch(void* const* d_in, const int* in_sizes, int n_in,
                              void* d_out, int out_size, void* d_ws, size_t ws_size,
                              hipStream_t stream) {
    const float* x      = (const float*)d_in[0];
    const int*   A      = (const int*)  d_in[1];
    const float* conv_w = (const float*)d_in[2];
    const float* conv_b = (const float*)d_in[3];
    const float* w_ih   = (const float*)d_in[4];
    const float* w_hh   = (const float*)d_in[5];
    const float* b_ih   = (const float*)d_in[6];
    const float* b_hh   = (const float*)d_in[7];
    float* out = (float*)d_out;

    char* ws = (char*)d_ws;
    __hip_bfloat16* P  = (__hip_bfloat16*)ws;                    // 5.25 MB
    size_t offGx = (size_t)TT * NA * OO * 2;
    __hip_bfloat16* gx = (__hip_bfloat16*)(ws + offGx);          // 21 MB
    size_t offW  = offGx + (size_t)TT * NA * GG * 2;
    unsigned short* wihb = (unsigned short*)(ws + offW);         // 32 KB
    unsigned short* whhb = wihb + 4 * OO * OO;                   // 32 KB
    float* biasT = (float*)(whhb + 4 * OO * OO);                 // 1 KB

    (void)hipFuncSetAttribute((const void*)gatemm_kernel,
                              hipFuncAttributeMaxDynamicSharedMemorySize,
                              32768);

    hipLaunchKernelGGL(proj_kernel, dim3(NA * TT / 16 + 1), dim3(256), 0, stream,
                       x, conv_w, conv_b, w_ih, w_hh, b_ih, b_hh,
                       P, wihb, whhb, biasT);
    hipLaunchKernelGGL(gatemm_kernel, dim3(NA * TT / 16), dim3(128), 32768,
                       stream, P, A, wihb, biasT, gx);
    hipLaunchKernelGGL(lstm_kernel, dim3(NA / 16), dim3(256), 0, stream,
                       gx, whhb, out);
}

// Round 11
// 131.227 us; speedup vs baseline: 1.0834x; 1.0834x over previous
//
#include <hip/hip_runtime.h>
#include <hip/hip_bf16.h>
#include <math.h>

#define NA 2048   // agents (2^11)
#define TT 20     // timesteps
#define KK 32     // neighbors
#define CC 32     // in channels
#define OO 64     // out channels / hidden
#define GG 256    // 4*OO gates

typedef __attribute__((ext_vector_type(8))) short short8;
typedef __attribute__((ext_vector_type(4))) float float4v;

__device__ __forceinline__ float fast_rcp(float x) {
    return __builtin_amdgcn_rcpf(x);
}
__device__ __forceinline__ float sigm(float x) {
    return fast_rcp(1.f + __expf(-x));
}
__device__ __forceinline__ float tanh_fast(float x) {
    return 1.f - 2.f * fast_rcp(1.f + __expf(2.f * x));
}
// bf16 RNE on raw bits (ties-to-even; NaN not expected here).
__device__ __forceinline__ unsigned cvt_rne(float f) {
    unsigned u = __float_as_uint(f);
    return (u + 0x7FFFu + ((u >> 16) & 1u)) >> 16;
}
__device__ __forceinline__ unsigned pack2(float a, float b) {
    return cvt_rne(a) | (cvt_rne(b) << 16);
}
__device__ __forceinline__ float bf_lo(unsigned u) {
    return __uint_as_float(u << 16);
}
__device__ __forceinline__ float bf_hi(unsigned u) {
    return __uint_as_float(u & 0xffff0000u);
}

// P[t][n][o] = sum_c x[n][t][c] * conv_w[o][c], stored bf16 (128B rows).
// Block 0 pre-converts w_ih/w_hh to bf16 and precomputes the folded gate
// bias (b_ih + b_hh + conv_b @ w_ih^T).
__global__ __launch_bounds__(256) void proj_kernel(
    const float* __restrict__ x, const float* __restrict__ conv_w,
    const float* __restrict__ conv_b, const float* __restrict__ w_ih,
    const float* __restrict__ w_hh, const float* __restrict__ b_ih,
    const float* __restrict__ b_hh,
    __hip_bfloat16* __restrict__ P, unsigned short* __restrict__ wihb,
    unsigned short* __restrict__ whhb, float* __restrict__ biasT)
{
    const int tid = threadIdx.x;
    if (blockIdx.x == 0) {   // prep block
        for (int e = tid; e < 4 * OO * OO; e += 256) {
            wihb[e] = (unsigned short)cvt_rne(w_ih[e]);
            whhb[e] = (unsigned short)cvt_rne(w_hh[e]);
        }
        float bj = b_ih[tid] + b_hh[tid];
        #pragma unroll
        for (int o = 0; o < OO; o += 4) {
            float4 cb = *(const float4*)(conv_b + o);
            float4 wr = *(const float4*)(w_ih + (size_t)tid * OO + o);
            bj = fmaf(cb.x, wr.x, bj); bj = fmaf(cb.y, wr.y, bj);
            bj = fmaf(cb.z, wr.z, bj); bj = fmaf(cb.w, wr.w, bj);
        }
        biasT[tid] = bj;
        return;
    }
    const int lane = tid & 63;
    const int wv = tid >> 6;
    float w[CC];
    #pragma unroll
    for (int c = 0; c < CC; c += 4) {
        float4 v = *(const float4*)(conv_w + lane * CC + c);
        w[c] = v.x; w[c + 1] = v.y; w[c + 2] = v.z; w[c + 3] = v.w;
    }
    const int rbase = (blockIdx.x - 1) * 16 + wv * 4;
    #pragma unroll
    for (int i = 0; i < 4; ++i) {
        int r = rbase + i;                    // r = n*TT + t (x row order)
        const float* xr = x + (size_t)r * CC;
        float a0 = 0.f, a1 = 0.f;
        #pragma unroll
        for (int c = 0; c < CC; c += 8) {
            float4 v = *(const float4*)(xr + c);
            float4 u = *(const float4*)(xr + c + 4);
            a0 = fmaf(v.x, w[c], a0);     a0 = fmaf(v.y, w[c + 1], a0);
            a0 = fmaf(v.z, w[c + 2], a0); a0 = fmaf(v.w, w[c + 3], a0);
            a1 = fmaf(u.x, w[c + 4], a1); a1 = fmaf(u.y, w[c + 5], a1);
            a1 = fmaf(u.z, w[c + 6], a1); a1 = fmaf(u.w, w[c + 7], a1);
        }
        int n = r / TT;
        int t = r - n * TT;
        ((unsigned short*)P)[(((size_t)t << 11) + n) * OO + lane] =
            (unsigned short)cvt_rne(a0 + a1);
    }
}

// Pure gather-max kernel, dword granularity, no LDS.
// R4-R10 lesson: dwordx4-per-thread gathers get register-serialized (R5/R6),
// LDS-slab versions hit conflicts/occupancy (R8) or compiler vmcnt(0) drains
// (R9/R10). Here: wave = 2 rows; lane = (row-half, ch-pair); one
// global_load_dword per neighbor = 2 coalesced 128B segments per inst;
// 16-deep batches are only 16 payload VGPRs so the allocator keeps them
// in flight. 5120 blocks -> 20/CU, 16 waves resident.
// feat[r][ch] (bf16) = max_k P_t[A[r][k]][ch] - P_t[self][ch].
__global__ __launch_bounds__(256, 4) void gather_kernel(
    const __hip_bfloat16* __restrict__ P, const int* __restrict__ A,
    unsigned* __restrict__ featw)
{
    const int tid = threadIdx.x;
    const int lane = tid & 63;
    const int wv = tid >> 6;
    const int bs = (blockIdx.x & 7) * 640 + (blockIdx.x >> 3);  // XCD swizzle
    const int r0 = bs << 3;                 // 8 rows/block, r = t*NA + n
    const int t = r0 >> 11;
    const unsigned short* Pt = (const unsigned short*)P + ((size_t)t << 17);

    const int rw = r0 + wv * 2;             // this wave's first row
    // lane L: av = A[rw + (L>>5)][L&31]  (one coalesced dword per lane)
    const int av = A[((size_t)rw << 5) + lane];
    const int half = lane >> 5;             // which of the 2 rows
    const int cp = lane & 31;               // channel pair (dword)
    const char* plane = (const char*)Pt + cp * 4;

    const int nself = (rw + half) & (NA - 1);
    const unsigned su = *(const unsigned*)(plane + ((size_t)nself << 7));

    float mlo = -INFINITY, mhi = -INFINITY;
    #pragma unroll
    for (int bb = 0; bb < 2; ++bb) {
        unsigned uv[16];                    // 16 VGPRs of in-flight payload
        #pragma unroll
        for (int g2 = 0; g2 < 16; ++g2) {
            int g = bb * 16 + g2;
            int i0 = __builtin_amdgcn_readlane(av, g);
            int i1 = __builtin_amdgcn_readlane(av, g + 32);
            int idx = half ? i1 : i0;
            uv[g2] = *(const unsigned*)(plane + ((size_t)idx << 7));
        }
        #pragma unroll
        for (int g2 = 0; g2 < 16; ++g2) {
            mlo = fmaxf(mlo, bf_lo(uv[g2]));
            mhi = fmaxf(mhi, bf_hi(uv[g2]));
        }
    }
    featw[((size_t)(rw + half) << 5) + cp] =
        pack2(mlo - bf_lo(su), mhi - bf_hi(su));
}

// Serial recurrence with FUSED input-gate matmul:
// gates = feat @ w_ih^T + h @ w_hh^T + bias  — both are the same 16x16x32
// MFMA shape, so wave wv (gate plane) runs 16 MFMA/step; feat A-frags are
// loaded straight from global (L2-hot, prefetched one step ahead).
// This eliminates the gx intermediate (21MB write + read + one launch).
__global__ __launch_bounds__(256, 2) void lstm_kernel(
    const unsigned short* __restrict__ feat,
    const unsigned short* __restrict__ wihb,
    const unsigned short* __restrict__ whhb,
    const float* __restrict__ biasT, float* __restrict__ out)
{
    const int tid = threadIdx.x;
    const int lane = tid & 63;
    const int wv = tid >> 6;          // gate plane
    const int l15 = lane & 15;
    const int q = lane >> 4;
    const int a0 = blockIdx.x * 16;
    const int a = tid >> 4;           // pointwise: agent 0..15
    const int c0 = (tid & 15) * 4;    // pointwise: first channel

    // B-frags: rows wv*64+ch of w_ih and w_hh (bf16, preconverted)
    short8 bfI[4][2], bfH[4][2];
    #pragma unroll
    for (int tt2 = 0; tt2 < 4; ++tt2) {
        int row = wv * 64 + tt2 * 16 + l15;
        #pragma unroll
        for (int ks = 0; ks < 2; ++ks) {
            bfI[tt2][ks] =
                *(const short8*)(wihb + ((size_t)row << 6) + ks * 32 + q * 8);
            bfH[tt2][ks] =
                *(const short8*)(whhb + ((size_t)row << 6) + ks * 32 + q * 8);
        }
    }
    // pointwise bias: biasT[g*64 + c0..c0+3] for g = 0..3
    float4 bias4[4];
    #pragma unroll
    for (int g = 0; g < 4; ++g)
        bias4[g] = *(const float4*)(biasT + g * 64 + c0);

    __shared__ __align__(16) unsigned short h_sh[16 * 72];  // bf16, pad 72
    __shared__ float gp[4][16][68];                         // gate planes

    {   // h = 0
        uint2 z; z.x = 0u; z.y = 0u;
        *(uint2*)&h_sh[a * 72 + c0] = z;
    }
    float cst[4] = {0.f, 0.f, 0.f, 0.f};

    // preload feat A-frags for t = 0
    short8 ff[2];
    #pragma unroll
    for (int ks = 0; ks < 2; ++ks)
        ff[ks] = *(const short8*)(
            feat + (((size_t)a0 + l15) << 6) + ks * 32 + q * 8);

    for (int t = 0; t < TT; ++t) {
        __syncthreads();  // h_sh ready (init or previous pointwise)

        float4v acc[4] = {{0.f, 0.f, 0.f, 0.f}, {0.f, 0.f, 0.f, 0.f},
                          {0.f, 0.f, 0.f, 0.f}, {0.f, 0.f, 0.f, 0.f}};
        #pragma unroll
        for (int ks = 0; ks < 2; ++ks) {
            short8 ah = *(const short8*)(&h_sh[l15 * 72 + ks * 32 + q * 8]);
            #pragma unroll
            for (int tt2 = 0; tt2 < 4; ++tt2) {
                acc[tt2] = __builtin_amdgcn_mfma_f32_16x16x32_bf16(
                    ff[ks], bfI[tt2][ks], acc[tt2], 0, 0, 0);
                acc[tt2] = __builtin_amdgcn_mfma_f32_16x16x32_bf16(
                    ah, bfH[tt2][ks], acc[tt2], 0, 0, 0);
            }
        }
        #pragma unroll
        for (int tt2 = 0; tt2 < 4; ++tt2)
            #pragma unroll
            for (int rg = 0; rg < 4; ++rg)
                gp[wv][q * 4 + rg][tt2 * 16 + l15] = acc[tt2][rg];

        // prefetch next step's feat frags while gp settles
        short8 ffn[2];
        int tn = (t + 1 < TT) ? t + 1 : t;
        #pragma unroll
        for (int ks = 0; ks < 2; ++ks)
            ffn[ks] = *(const short8*)(
                feat + ((((size_t)tn << 11) + a0 + l15) << 6) + ks * 32 + q * 8);
        __syncthreads();  // gp ready

        float4 gv0 = *(const float4*)&gp[0][a][c0];
        float4 gv1 = *(const float4*)&gp[1][a][c0];
        float4 gv2 = *(const float4*)&gp[2][a][c0];
        float4 gv3 = *(const float4*)&gp[3][a][c0];
        float hv[4];
        {
            float gi[4] = {gv0.x + bias4[0].x, gv0.y + bias4[0].y,
                           gv0.z + bias4[0].z, gv0.w + bias4[0].w};
            float gf[4] = {gv1.x + bias4[1].x, gv1.y + bias4[1].y,
                           gv1.z + bias4[1].z, gv1.w + bias4[1].w};
            float gz[4] = {gv2.x + bias4[2].x, gv2.y + bias4[2].y,
                           gv2.z + bias4[2].z, gv2.w + bias4[2].w};
            float go[4] = {gv3.x + bias4[3].x, gv3.y + bias4[3].y,
                           gv3.z + bias4[3].z, gv3.w + bias4[3].w};
            #pragma unroll
            for (int e = 0; e < 4; ++e) {
                float ig = sigm(gi[e]);
                float fg = sigm(gf[e]);
                float zg = tanh_fast(gz[e]);
                float og = sigm(go[e]);
                cst[e] = fmaf(fg, cst[e], ig * zg);
                hv[e] = og * tanh_fast(cst[e]);
            }
        }
        {
            uint2 pk;
            pk.x = pack2(hv[0], hv[1]);
            pk.y = pack2(hv[2], hv[3]);
            *(uint2*)&h_sh[a * 72 + c0] = pk;
        }
        float4 ho; ho.x = hv[0]; ho.y = hv[1]; ho.z = hv[2]; ho.w = hv[3];
        *(float4*)(out + (((size_t)(a0 + a) * TT + t) << 6) + c0) = ho;
        if (t == TT - 1) {
            size_t hb = (size_t)NA * TT * OO;
            *(float4*)(out + hb + ((size_t)(a0 + a) << 6) + c0) = ho;
            float4 co; co.x = cst[0]; co.y = cst[1]; co.z = cst[2]; co.w = cst[3];
            *(float4*)(out + hb + ((size_t)NA << 6) + ((size_t)(a0 + a) << 6) + c0) = co;
        }
        ff[0] = ffn[0]; ff[1] = ffn[1];
    }
}

extern "C" void kernel_launch(void* const* d_in, const int* in_sizes, int n_in,
                              void* d_out, int out_size, void* d_ws, size_t ws_size,
                              hipStream_t stream) {
    const float* x      = (const float*)d_in[0];
    const int*   A      = (const int*)  d_in[1];
    const float* conv_w = (const float*)d_in[2];
    const float* conv_b = (const float*)d_in[3];
    const float* w_ih   = (const float*)d_in[4];
    const float* w_hh   = (const float*)d_in[5];
    const float* b_ih   = (const float*)d_in[6];
    const float* b_hh   = (const float*)d_in[7];
    float* out = (float*)d_out;

    char* ws = (char*)d_ws;
    __hip_bfloat16* P  = (__hip_bfloat16*)ws;                    // 5.25 MB
    size_t offF = (size_t)TT * NA * OO * 2;
    unsigned* featw = (unsigned*)(ws + offF);                    // 5.25 MB
    size_t offW = offF + (size_t)TT * NA * OO * 2;
    unsigned short* wihb = (unsigned short*)(ws + offW);         // 32 KB
    unsigned short* whhb = wihb + 4 * OO * OO;                   // 32 KB
    float* biasT = (float*)(whhb + 4 * OO * OO);                 // 1 KB

    hipLaunchKernelGGL(proj_kernel, dim3(NA * TT / 16 + 1), dim3(256), 0, stream,
                       x, conv_w, conv_b, w_ih, w_hh, b_ih, b_hh,
                       P, wihb, whhb, biasT);
    hipLaunchKernelGGL(gather_kernel, dim3(NA * TT / 8), dim3(256), 0, stream,
                       P, A, featw);
    hipLaunchKernelGGL(lstm_kernel, dim3(NA / 16), dim3(256), 0, stream,
                       (const unsigned short*)featw, wihb, whhb, biasT, out);
}

// Round 12
// 127.596 us; speedup vs baseline: 1.1143x; 1.0285x over previous
//
#include <hip/hip_runtime.h>
#include <hip/hip_bf16.h>
#include <math.h>

#define NA 2048   // agents (2^11)
#define TT 20     // timesteps
#define KK 32     // neighbors
#define CC 32     // in channels
#define OO 64     // out channels / hidden
#define GG 256    // 4*OO gates

typedef __attribute__((ext_vector_type(8))) short short8;
typedef __attribute__((ext_vector_type(4))) float float4v;

__device__ __forceinline__ float fast_rcp(float x) {
    return __builtin_amdgcn_rcpf(x);
}
__device__ __forceinline__ float sigm(float x) {
    return fast_rcp(1.f + __expf(-x));
}
__device__ __forceinline__ float tanh_fast(float x) {
    return 1.f - 2.f * fast_rcp(1.f + __expf(2.f * x));
}
// bf16 RNE on raw bits (ties-to-even; NaN not expected here).
__device__ __forceinline__ unsigned cvt_rne(float f) {
    unsigned u = __float_as_uint(f);
    return (u + 0x7FFFu + ((u >> 16) & 1u)) >> 16;
}
__device__ __forceinline__ unsigned pack2(float a, float b) {
    return cvt_rne(a) | (cvt_rne(b) << 16);
}
__device__ __forceinline__ float bf_lo(unsigned u) {
    return __uint_as_float(u << 16);
}
__device__ __forceinline__ float bf_hi(unsigned u) {
    return __uint_as_float(u & 0xffff0000u);
}

// P[t][n][o] = sum_c x[n][t][c] * conv_w[o][c], stored bf16 (128B rows).
// Block 0 pre-converts w_ih/w_hh to bf16 and precomputes the folded gate
// bias (b_ih + b_hh + conv_b @ w_ih^T).
__global__ __launch_bounds__(256) void proj_kernel(
    const float* __restrict__ x, const float* __restrict__ conv_w,
    const float* __restrict__ conv_b, const float* __restrict__ w_ih,
    const float* __restrict__ w_hh, const float* __restrict__ b_ih,
    const float* __restrict__ b_hh,
    __hip_bfloat16* __restrict__ P, unsigned short* __restrict__ wihb,
    unsigned short* __restrict__ whhb, float* __restrict__ biasT)
{
    const int tid = threadIdx.x;
    if (blockIdx.x == 0) {   // prep block
        for (int e = tid; e < 4 * OO * OO; e += 256) {
            wihb[e] = (unsigned short)cvt_rne(w_ih[e]);
            whhb[e] = (unsigned short)cvt_rne(w_hh[e]);
        }
        float bj = b_ih[tid] + b_hh[tid];
        #pragma unroll
        for (int o = 0; o < OO; o += 4) {
            float4 cb = *(const float4*)(conv_b + o);
            float4 wr = *(const float4*)(w_ih + (size_t)tid * OO + o);
            bj = fmaf(cb.x, wr.x, bj); bj = fmaf(cb.y, wr.y, bj);
            bj = fmaf(cb.z, wr.z, bj); bj = fmaf(cb.w, wr.w, bj);
        }
        biasT[tid] = bj;
        return;
    }
    const int lane = tid & 63;
    const int wv = tid >> 6;
    float w[CC];
    #pragma unroll
    for (int c = 0; c < CC; c += 4) {
        float4 v = *(const float4*)(conv_w + lane * CC + c);
        w[c] = v.x; w[c + 1] = v.y; w[c + 2] = v.z; w[c + 3] = v.w;
    }
    const int rbase = (blockIdx.x - 1) * 16 + wv * 4;
    #pragma unroll
    for (int i = 0; i < 4; ++i) {
        int r = rbase + i;                    // r = n*TT + t (x row order)
        const float* xr = x + (size_t)r * CC;
        float a0 = 0.f, a1 = 0.f;
        #pragma unroll
        for (int c = 0; c < CC; c += 8) {
            float4 v = *(const float4*)(xr + c);
            float4 u = *(const float4*)(xr + c + 4);
            a0 = fmaf(v.x, w[c], a0);     a0 = fmaf(v.y, w[c + 1], a0);
            a0 = fmaf(v.z, w[c + 2], a0); a0 = fmaf(v.w, w[c + 3], a0);
            a1 = fmaf(u.x, w[c + 4], a1); a1 = fmaf(u.y, w[c + 5], a1);
            a1 = fmaf(u.z, w[c + 6], a1); a1 = fmaf(u.w, w[c + 7], a1);
        }
        int n = r / TT;
        int t = r - n * TT;
        ((unsigned short*)P)[(((size_t)t << 11) + n) * OO + lane] =
            (unsigned short)cvt_rne(a0 + a1);
    }
}

// Pure gather-max kernel, v2: 4 rows/wave, dwordx2 per lane.
// One load inst covers 4 rows x 128B (4 coalesced segments) — half the
// load insts of R11's dword version. Addressing = 1 broadcast ds_read_b32
// per neighbor (A-rows staged wave-locally, in-order DS, no barrier).
// Payload 32 VGPR/batch — small enough that the allocator keeps the
// 16-deep batch in flight (R11 lesson: payload pressure decides depth).
__global__ __launch_bounds__(256, 4) void gather_kernel(
    const __hip_bfloat16* __restrict__ P, const int* __restrict__ A,
    unsigned* __restrict__ featw)
{
    __shared__ int A_sh[4][128];            // per-wave: 4 rows x 32 idx
    const int tid = threadIdx.x;
    const int lane = tid & 63;
    const int wv = tid >> 6;
    const int bs = (blockIdx.x & 7) * 320 + (blockIdx.x >> 3);  // XCD swizzle
    const int r0 = bs << 4;                 // 16 rows/block, r = t*NA + n
    const int t = r0 >> 11;                 // block never crosses a t-slab
    const unsigned short* Pt = (const unsigned short*)P + ((size_t)t << 17);

    const int rw = r0 + wv * 4;             // wave's first row
    // stage this wave's 4 A-rows (128 ints) wave-locally; same-wave DS
    // ordering makes the later reads safe without a barrier.
    ((int2*)A_sh[wv])[lane] = ((const int2*)(A + ((size_t)rw << 5)))[lane];

    const int i_row = lane >> 4;            // 0..3: row within wave
    const int oc8 = lane & 15;              // 8B chunk (4 channels)
    const char* plane = (const char*)Pt + oc8 * 8;
    const int* myA = &A_sh[wv][i_row * 32];

    const int nself = (rw + i_row) & (NA - 1);
    const uint2 su = *(const uint2*)(plane + ((size_t)nself << 7));

    float m0 = -INFINITY, m1 = -INFINITY, m2 = -INFINITY, m3 = -INFINITY;
    #pragma unroll
    for (int bb = 0; bb < 2; ++bb) {
        int idx[16];
        #pragma unroll
        for (int g = 0; g < 16; ++g)        // broadcast ds_read_b32
            idx[g] = myA[bb * 16 + g];
        uint2 uv[16];                       // 32 VGPRs in-flight payload
        #pragma unroll
        for (int g = 0; g < 16; ++g)
            uv[g] = *(const uint2*)(plane + ((size_t)idx[g] << 7));
        #pragma unroll
        for (int g = 0; g < 16; ++g) {
            m0 = fmaxf(m0, bf_lo(uv[g].x)); m1 = fmaxf(m1, bf_hi(uv[g].x));
            m2 = fmaxf(m2, bf_lo(uv[g].y)); m3 = fmaxf(m3, bf_hi(uv[g].y));
        }
    }
    uint2 pk;
    pk.x = pack2(m0 - bf_lo(su.x), m1 - bf_hi(su.x));
    pk.y = pack2(m2 - bf_lo(su.y), m3 - bf_hi(su.y));
    *(uint2*)&featw[((size_t)(rw + i_row) << 5) + oc8 * 2] = pk;
}

// Serial recurrence with FUSED input-gate matmul (R11 structure):
// gates = feat @ w_ih^T + h @ w_hh^T + bias; wave wv = gate plane,
// 16 MFMA/step; feat A-frags prefetched from global one step ahead.
__global__ __launch_bounds__(256, 2) void lstm_kernel(
    const unsigned short* __restrict__ feat,
    const unsigned short* __restrict__ wihb,
    const unsigned short* __restrict__ whhb,
    const float* __restrict__ biasT, float* __restrict__ out)
{
    const int tid = threadIdx.x;
    const int lane = tid & 63;
    const int wv = tid >> 6;          // gate plane
    const int l15 = lane & 15;
    const int q = lane >> 4;
    const int a0 = blockIdx.x * 16;
    const int a = tid >> 4;           // pointwise: agent 0..15
    const int c0 = (tid & 15) * 4;    // pointwise: first channel

    // B-frags: rows wv*64+ch of w_ih and w_hh (bf16, preconverted)
    short8 bfI[4][2], bfH[4][2];
    #pragma unroll
    for (int tt2 = 0; tt2 < 4; ++tt2) {
        int row = wv * 64 + tt2 * 16 + l15;
        #pragma unroll
        for (int ks = 0; ks < 2; ++ks) {
            bfI[tt2][ks] =
                *(const short8*)(wihb + ((size_t)row << 6) + ks * 32 + q * 8);
            bfH[tt2][ks] =
                *(const short8*)(whhb + ((size_t)row << 6) + ks * 32 + q * 8);
        }
    }
    float4 bias4[4];
    #pragma unroll
    for (int g = 0; g < 4; ++g)
        bias4[g] = *(const float4*)(biasT + g * 64 + c0);

    __shared__ __align__(16) unsigned short h_sh[16 * 72];  // bf16, pad 72
    __shared__ float gp[4][16][68];                         // gate planes

    {   // h = 0
        uint2 z; z.x = 0u; z.y = 0u;
        *(uint2*)&h_sh[a * 72 + c0] = z;
    }
    float cst[4] = {0.f, 0.f, 0.f, 0.f};

    // preload feat A-frags for t = 0
    short8 ff[2];
    #pragma unroll
    for (int ks = 0; ks < 2; ++ks)
        ff[ks] = *(const short8*)(
            feat + (((size_t)a0 + l15) << 6) + ks * 32 + q * 8);

    for (int t = 0; t < TT; ++t) {
        __syncthreads();  // h_sh ready (init or previous pointwise)

        float4v acc[4] = {{0.f, 0.f, 0.f, 0.f}, {0.f, 0.f, 0.f, 0.f},
                          {0.f, 0.f, 0.f, 0.f}, {0.f, 0.f, 0.f, 0.f}};
        #pragma unroll
        for (int ks = 0; ks < 2; ++ks) {
            short8 ah = *(const short8*)(&h_sh[l15 * 72 + ks * 32 + q * 8]);
            #pragma unroll
            for (int tt2 = 0; tt2 < 4; ++tt2) {
                acc[tt2] = __builtin_amdgcn_mfma_f32_16x16x32_bf16(
                    ff[ks], bfI[tt2][ks], acc[tt2], 0, 0, 0);
                acc[tt2] = __builtin_amdgcn_mfma_f32_16x16x32_bf16(
                    ah, bfH[tt2][ks], acc[tt2], 0, 0, 0);
            }
        }
        #pragma unroll
        for (int tt2 = 0; tt2 < 4; ++tt2)
            #pragma unroll
            for (int rg = 0; rg < 4; ++rg)
                gp[wv][q * 4 + rg][tt2 * 16 + l15] = acc[tt2][rg];

        // prefetch next step's feat frags while gp settles
        short8 ffn[2];
        int tn = (t + 1 < TT) ? t + 1 : t;
        #pragma unroll
        for (int ks = 0; ks < 2; ++ks)
            ffn[ks] = *(const short8*)(
                feat + ((((size_t)tn << 11) + a0 + l15) << 6) + ks * 32 + q * 8);
        __syncthreads();  // gp ready

        float4 gv0 = *(const float4*)&gp[0][a][c0];
        float4 gv1 = *(const float4*)&gp[1][a][c0];
        float4 gv2 = *(const float4*)&gp[2][a][c0];
        float4 gv3 = *(const float4*)&gp[3][a][c0];
        float hv[4];
        {
            float gi[4] = {gv0.x + bias4[0].x, gv0.y + bias4[0].y,
                           gv0.z + bias4[0].z, gv0.w + bias4[0].w};
            float gf[4] = {gv1.x + bias4[1].x, gv1.y + bias4[1].y,
                           gv1.z + bias4[1].z, gv1.w + bias4[1].w};
            float gz[4] = {gv2.x + bias4[2].x, gv2.y + bias4[2].y,
                           gv2.z + bias4[2].z, gv2.w + bias4[2].w};
            float go[4] = {gv3.x + bias4[3].x, gv3.y + bias4[3].y,
                           gv3.z + bias4[3].z, gv3.w + bias4[3].w};
            #pragma unroll
            for (int e = 0; e < 4; ++e) {
                float ig = sigm(gi[e]);
                float fg = sigm(gf[e]);
                float zg = tanh_fast(gz[e]);
                float og = sigm(go[e]);
                cst[e] = fmaf(fg, cst[e], ig * zg);
                hv[e] = og * tanh_fast(cst[e]);
            }
        }
        {
            uint2 pk;
            pk.x = pack2(hv[0], hv[1]);
            pk.y = pack2(hv[2], hv[3]);
            *(uint2*)&h_sh[a * 72 + c0] = pk;
        }
        float4 ho; ho.x = hv[0]; ho.y = hv[1]; ho.z = hv[2]; ho.w = hv[3];
        *(float4*)(out + (((size_t)(a0 + a) * TT + t) << 6) + c0) = ho;
        if (t == TT - 1) {
            size_t hb = (size_t)NA * TT * OO;
            *(float4*)(out + hb + ((size_t)(a0 + a) << 6) + c0) = ho;
            float4 co; co.x = cst[0]; co.y = cst[1]; co.z = cst[2]; co.w = cst[3];
            *(float4*)(out + hb + ((size_t)NA << 6) + ((size_t)(a0 + a) << 6) + c0) = co;
        }
        ff[0] = ffn[0]; ff[1] = ffn[1];
    }
}

extern "C" void kernel_launch(void* const* d_in, const int* in_sizes, int n_in,
                              void* d_out, int out_size, void* d_ws, size_t ws_size,
                              hipStream_t stream) {
    const float* x      = (const float*)d_in[0];
    const int*   A      = (const int*)  d_in[1];
    const float* conv_w = (const float*)d_in[2];
    const float* conv_b = (const float*)d_in[3];
    const float* w_ih   = (const float*)d_in[4];
    const float* w_hh   = (const float*)d_in[5];
    const float* b_ih   = (const float*)d_in[6];
    const float* b_hh   = (const float*)d_in[7];
    float* out = (float*)d_out;

    char* ws = (char*)d_ws;
    __hip_bfloat16* P  = (__hip_bfloat16*)ws;                    // 5.25 MB
    size_t offF = (size_t)TT * NA * OO * 2;
    unsigned* featw = (unsigned*)(ws + offF);                    // 5.25 MB
    size_t offW = offF + (size_t)TT * NA * OO * 2;
    unsigned short* wihb = (unsigned short*)(ws + offW);         // 32 KB
    unsigned short* whhb = wihb + 4 * OO * OO;                   // 32 KB
    float* biasT = (float*)(whhb + 4 * OO * OO);                 // 1 KB

    hipLaunchKernelGGL(proj_kernel, dim3(NA * TT / 16 + 1), dim3(256), 0, stream,
                       x, conv_w, conv_b, w_ih, w_hh, b_ih, b_hh,
                       P, wihb, whhb, biasT);
    hipLaunchKernelGGL(gather_kernel, dim3(NA * TT / 16), dim3(256), 0, stream,
                       P, A, featw);
    hipLaunchKernelGGL(lstm_kernel, dim3(NA / 16), dim3(256), 0, stream,
                       (const unsigned short*)featw, wihb, whhb, biasT, out);
}